// Round 1
// baseline (150.975 us; speedup 1.0000x reference)
//
#include <hip/hip_runtime.h>

#define LDSP 136  // padded row stride (elements); 272B rows keep b128 reads conflict-minimal, 16B aligned

typedef _Float16 h8 __attribute__((ext_vector_type(8)));
typedef _Float16 h4 __attribute__((ext_vector_type(4)));
typedef float    f4 __attribute__((ext_vector_type(4)));

// ---- pre-kernel: convert Wq/Wk/Wv fp32 -> f16 into workspace ----
__global__ void wconv(const float* __restrict__ Wq, const float* __restrict__ Wk,
                      const float* __restrict__ Wv, _Float16* __restrict__ o) {
    int v = blockIdx.x * 256 + threadIdx.x;      // 12288 threads, 4 elems each
    int arr = v >> 12;
    int off = (v & 4095) * 4;
    const float* s = arr == 0 ? Wq : (arr == 1 ? Wk : Wv);
    f4 f = *(const f4*)(s + off);
    h4 h = {(_Float16)f.x, (_Float16)f.y, (_Float16)f.z, (_Float16)f.w};
    *(h4*)(o + arr * 16384 + off) = h;
}

// One workgroup per window. 512 threads = 8 waves; wave w owns 16-row strip [16w,16w+16).
__global__ __launch_bounds__(512, 2) void attn(
    const float* __restrict__ x, const _Float16* __restrict__ Wb,
    const float* __restrict__ bq, const float* __restrict__ bk,
    const float* __restrict__ bv, float* __restrict__ out) {
    __shared__ _Float16 Xs[128 * LDSP];  // X tile; reused as Ps (attn probs) in phase 2/3
    __shared__ _Float16 Qs[128 * LDSP];  // Q[w][d]
    __shared__ _Float16 Ks[128 * LDSP];  // K[u][d]
    __shared__ _Float16 Vs[128 * LDSP];  // V transposed: Vs[d][u]

    const int tid  = threadIdx.x;
    const int wave = tid >> 6;
    const int lane = tid & 63;
    const int quad = lane >> 4;
    const int l16  = lane & 15;
    const int wb   = wave * 16;  // this wave's strip
    const size_t base = (size_t)blockIdx.x * (128 * 128);

    const _Float16* Wqb = Wb;
    const _Float16* Wkb = Wb + 16384;
    const _Float16* Wvb = Wb + 32768;

    // ---- stage X tile (fp32 global -> f16 LDS), coalesced float4 ----
    for (int i = tid; i < 4096; i += 512) {
        int idx = i * 4, row = idx >> 7, col = idx & 127;
        f4 f = *(const f4*)(x + base + idx);
        h4 h = {(_Float16)f.x, (_Float16)f.y, (_Float16)f.z, (_Float16)f.w};
        *(h4*)(&Xs[row * LDSP + col]) = h;
    }
    __syncthreads();

    // ---- phase 1: Q^T, K^T, V in one pass over Xs ----
    // Q^T[d][w] = sum_e Wq[d][e] X[w][e]   (wave owns d-strip; A = Wq rows, B = Xs)
    // V[u][d]   = sum_e X[u][e] Wv[d][e]   (wave owns d-strip; A = Xs, B = Wv rows)
    {
        f4 accQ[8], accK[8], accV[8];
        h8 aQ[4], aK[4], aV[4];
        for (int e0 = 0; e0 < 4; ++e0) {
            aQ[e0] = *(const h8*)(Wqb + (wb + l16) * 128 + e0 * 32 + quad * 8);
            aK[e0] = *(const h8*)(Wkb + (wb + l16) * 128 + e0 * 32 + quad * 8);
            aV[e0] = *(const h8*)(Wvb + (wb + l16) * 128 + e0 * 32 + quad * 8);
        }
        f4 bq4 = *(const f4*)(bq + wb + quad * 4);
        f4 bk4 = *(const f4*)(bk + wb + quad * 4);
        float bvv = bv[wb + l16];
        for (int t = 0; t < 8; ++t) {
            accQ[t] = bq4;
            accK[t] = bk4;
            accV[t] = (f4){bvv, bvv, bvv, bvv};
        }
        for (int e0 = 0; e0 < 4; ++e0) {
            h8 b[8];
            for (int nt = 0; nt < 8; ++nt)
                b[nt] = *(const h8*)(&Xs[(nt * 16 + l16) * LDSP + e0 * 32 + quad * 8]);
            for (int nt = 0; nt < 8; ++nt) {
                accQ[nt] = __builtin_amdgcn_mfma_f32_16x16x32_f16(aQ[e0], b[nt], accQ[nt], 0, 0, 0);
                accK[nt] = __builtin_amdgcn_mfma_f32_16x16x32_f16(aK[e0], b[nt], accK[nt], 0, 0, 0);
                accV[nt] = __builtin_amdgcn_mfma_f32_16x16x32_f16(b[nt], aV[e0], accV[nt], 0, 0, 0);
            }
        }
        // Q^T/K^T C/D: col = w = nt*16+l16, rows d = wb+quad*4+r  -> packed write Qs[w][d]
        for (int nt = 0; nt < 8; ++nt) {
            f4 v = accQ[nt];
            h4 h = {(_Float16)v.x, (_Float16)v.y, (_Float16)v.z, (_Float16)v.w};
            *(h4*)(&Qs[(nt * 16 + l16) * LDSP + wb + quad * 4]) = h;
            v = accK[nt];
            h4 g = {(_Float16)v.x, (_Float16)v.y, (_Float16)v.z, (_Float16)v.w};
            *(h4*)(&Ks[(nt * 16 + l16) * LDSP + wb + quad * 4]) = g;
        }
        // V C/D: col = d = wb+l16, rows u = mt*16+quad*4+r -> packed transposed write Vs[d][u]
        for (int mt = 0; mt < 8; ++mt) {
            f4 v = accV[mt];
            h4 h = {(_Float16)v.x, (_Float16)v.y, (_Float16)v.z, (_Float16)v.w};
            *(h4*)(&Vs[(wb + l16) * LDSP + mt * 16 + quad * 4]) = h;
        }
    }
    __syncthreads();

    // ---- phase 2: S^T[u][w] = sum_d K[u][d] Q[w][d]; wave owns w-strip (N dim) ----
    f4 acc[8];
    for (int mt = 0; mt < 8; ++mt) acc[mt] = (f4){0.f, 0.f, 0.f, 0.f};
    for (int d0 = 0; d0 < 4; ++d0) {
        h8 bqf = *(const h8*)(&Qs[(wb + l16) * LDSP + d0 * 32 + quad * 8]);
        h8 a[8];
        for (int mt = 0; mt < 8; ++mt)
            a[mt] = *(const h8*)(&Ks[(mt * 16 + l16) * LDSP + d0 * 32 + quad * 8]);
        for (int mt = 0; mt < 8; ++mt)
            acc[mt] = __builtin_amdgcn_mfma_f32_16x16x32_f16(a[mt], bqf, acc[mt], 0, 0, 0);
    }
    // softmax over u for this lane's column w = wb + l16 (values spread across quads)
    {
        float m = -1e30f;
        for (int mt = 0; mt < 8; ++mt) {
            f4 v = acc[mt];
            m = fmaxf(m, fmaxf(fmaxf(v.x, v.y), fmaxf(v.z, v.w)));
        }
        m = fmaxf(m, __shfl_xor(m, 16, 64));
        m = fmaxf(m, __shfl_xor(m, 32, 64));
        float s = 0.f;
        for (int mt = 0; mt < 8; ++mt) {
            f4 v = acc[mt];
            v.x = __expf(v.x - m); v.y = __expf(v.y - m);
            v.z = __expf(v.z - m); v.w = __expf(v.w - m);
            acc[mt] = v;
            s += v.x + v.y + v.z + v.w;
        }
        s += __shfl_xor(s, 16, 64);
        s += __shfl_xor(s, 32, 64);
        float inv = 1.0f / s;
        // P quad-regs are u-contiguous -> packed write Ps[w][u] (reuses Xs; X is dead)
        _Float16* Ps = Xs;
        for (int mt = 0; mt < 8; ++mt) {
            f4 v = acc[mt];
            h4 h = {(_Float16)(v.x * inv), (_Float16)(v.y * inv),
                    (_Float16)(v.z * inv), (_Float16)(v.w * inv)};
            *(h4*)(&Ps[(wb + l16) * LDSP + mt * 16 + quad * 4]) = h;
        }
    }
    // no barrier needed: this wave reads only its own Ps rows; Vs was fenced by the earlier barrier

    // ---- phase 3: O[w][d] = sum_u P[w][u] V[u][d]; wave owns w-strip (M dim) ----
    for (int nt = 0; nt < 8; ++nt) acc[nt] = (f4){0.f, 0.f, 0.f, 0.f};
    for (int u0 = 0; u0 < 4; ++u0) {
        h8 ap = *(const h8*)(&Xs[(wb + l16) * LDSP + u0 * 32 + quad * 8]);  // Ps
        h8 b[8];
        for (int nt = 0; nt < 8; ++nt)
            b[nt] = *(const h8*)(&Vs[(nt * 16 + l16) * LDSP + u0 * 32 + quad * 8]);
        for (int nt = 0; nt < 8; ++nt)
            acc[nt] = __builtin_amdgcn_mfma_f32_16x16x32_f16(ap, b[nt], acc[nt], 0, 0, 0);
    }
    // C/D: col = d = nt*16+l16, rows w = wb+quad*4+r -> 64B-segment coalesced dword stores
    float* ob = out + base;
    for (int nt = 0; nt < 8; ++nt) {
        f4 v = acc[nt];
        int w0 = wb + quad * 4;
        int d  = nt * 16 + l16;
        ob[(size_t)(w0 + 0) * 128 + d] = v.x;
        ob[(size_t)(w0 + 1) * 128 + d] = v.y;
        ob[(size_t)(w0 + 2) * 128 + d] = v.z;
        ob[(size_t)(w0 + 3) * 128 + d] = v.w;
    }
}

extern "C" void kernel_launch(void* const* d_in, const int* in_sizes, int n_in,
                              void* d_out, int out_size, void* d_ws, size_t ws_size,
                              hipStream_t stream) {
    const float* x  = (const float*)d_in[0];
    const float* Wq = (const float*)d_in[1];
    const float* bq = (const float*)d_in[2];
    const float* Wk = (const float*)d_in[3];
    const float* bk = (const float*)d_in[4];
    const float* Wv = (const float*)d_in[5];
    const float* bv = (const float*)d_in[6];
    _Float16* Wb = (_Float16*)d_ws;  // 3 * 16384 f16 = 96 KiB scratch

    wconv<<<48, 256, 0, stream>>>(Wq, Wk, Wv, Wb);
    attn<<<1024, 512, 0, stream>>>(x, Wb, bq, bk, bv, (float*)d_out);
}

// Round 2
// 142.464 us; speedup vs baseline: 1.0597x; 1.0597x over previous
//
#include <hip/hip_runtime.h>

#define LDSP 136  // padded row stride; 272B rows -> 4-bank rotation per row, b128 reads conflict-minimal

typedef _Float16 h8 __attribute__((ext_vector_type(8)));
typedef _Float16 h4 __attribute__((ext_vector_type(4)));
typedef float    f4 __attribute__((ext_vector_type(4)));

// ---- prep 1: Mt[f][e] = sum_d Wk[d][f] * Wq[d][e]  (f16), 64 blocks x 256 ----
// softmax(QK^T) == softmax(X Mt^T X^T + 1 * (ck . X^T)) -- row-constant terms drop.
__global__ void prep_mt(const float* __restrict__ Wq, const float* __restrict__ Wk,
                        _Float16* __restrict__ Mt) {
    int idx = blockIdx.x * 256 + threadIdx.x;  // 16384 entries
    int e = idx & 127, f = idx >> 7;
    float acc = 0.f;
    for (int d = 0; d < 128; ++d)
        acc += Wk[d * 128 + f] * Wq[d * 128 + e];  // Wq read coalesced over e; Wk uniform per wave
    Mt[idx] = (_Float16)acc;
}

// ---- prep 2: Wv fp32->f16; ck[f] = sum_d bq[d]*Wk[d][f]; 1 block x 256 ----
__global__ void prep_rest(const float* __restrict__ Wv, const float* __restrict__ Wk,
                          const float* __restrict__ bq, _Float16* __restrict__ Wvh,
                          float* __restrict__ ck) {
    int t = threadIdx.x;
    for (int i = 0; i < 16; ++i) {
        int off = (t + i * 256) * 4;
        f4 f = *(const f4*)(Wv + off);
        h4 h = {(_Float16)f.x, (_Float16)f.y, (_Float16)f.z, (_Float16)f.w};
        *(h4*)(Wvh + off) = h;
    }
    if (t < 128) {
        float acc = 0.f;
        for (int d = 0; d < 128; ++d) acc += bq[d] * Wk[d * 128 + t];
        ck[t] = acc;
    }
}

// One persistent block per CU; each handles 4 consecutive windows, prefetching
// the next window's X into registers while computing the current one.
__global__ __launch_bounds__(512, 2) void attn(
    const float* __restrict__ x, const _Float16* __restrict__ Mt,
    const _Float16* __restrict__ Wvh, const float* __restrict__ ck,
    const float* __restrict__ bv, float* __restrict__ out) {
    __shared__ _Float16 Xs[2][128 * LDSP];  // double-buffered X (f16)
    __shared__ _Float16 Ts[128 * LDSP];     // T'[w][f]; own-strip rows reused as P[w][u]
    __shared__ _Float16 Vs[128 * LDSP];     // V transposed: Vs[d][u]

    const int tid  = threadIdx.x;
    const int wave = tid >> 6;
    const int lane = tid & 63;
    const int quad = lane >> 4;
    const int l16  = lane & 15;
    const int wb   = wave * 16;

    // persistent weight fragments (live across all 4 windows)
    h8 aT[4], aV[4];
    for (int e0 = 0; e0 < 4; ++e0) {
        aT[e0] = *(const h8*)(Mt  + (wb + l16) * 128 + e0 * 32 + quad * 8);
        aV[e0] = *(const h8*)(Wvh + (wb + l16) * 128 + e0 * 32 + quad * 8);
    }
    f4 ck4  = *(const f4*)(ck + wb + quad * 4);
    float bvv = bv[wb + l16];

    const size_t base0 = (size_t)blockIdx.x * 4 * (128 * 128);

    // prefetch window 0 into registers
    f4 pf[8];
    for (int j = 0; j < 8; ++j)
        pf[j] = *(const f4*)(x + base0 + 4 * tid + 2048 * j);

    for (int it = 0; it < 4; ++it) {
        _Float16* X = Xs[it & 1];

        // ---- stage: convert prefetched regs -> X (f16 LDS) ----
        for (int j = 0; j < 8; ++j) {
            int idx = 4 * tid + 2048 * j;
            int row = idx >> 7, col = idx & 127;
            f4 f = pf[j];
            h4 h = {(_Float16)f.x, (_Float16)f.y, (_Float16)f.z, (_Float16)f.w};
            *(h4*)(&X[row * LDSP + col]) = h;
        }
        __syncthreads();  // X ready; also fences prev window's Ts/Vs readers

        // ---- issue prefetch for next window (completes during phases 1-2) ----
        if (it < 3) {
            const float* nx = x + base0 + (size_t)(it + 1) * (128 * 128);
            for (int j = 0; j < 8; ++j)
                pf[j] = *(const f4*)(nx + 4 * tid + 2048 * j);
        }

        // ---- phase 1: T'^T[f][w] = sum_e Mt[f][e] X[w][e] + ck_f ; V[u][d] ----
        {
            f4 accT[8], accV[8];
            for (int t = 0; t < 8; ++t) {
                accT[t] = ck4;
                accV[t] = (f4){bvv, bvv, bvv, bvv};
            }
            for (int e0 = 0; e0 < 4; ++e0) {
                h8 b[8];
                for (int nt = 0; nt < 8; ++nt)
                    b[nt] = *(const h8*)(&X[(nt * 16 + l16) * LDSP + e0 * 32 + quad * 8]);
                for (int nt = 0; nt < 8; ++nt) {
                    accT[nt] = __builtin_amdgcn_mfma_f32_16x16x32_f16(aT[e0], b[nt], accT[nt], 0, 0, 0);
                    accV[nt] = __builtin_amdgcn_mfma_f32_16x16x32_f16(b[nt], aV[e0], accV[nt], 0, 0, 0);
                }
            }
            // T' C/D: col = w = nt*16+l16, row = f = wb+quad*4+r -> packed write Ts[w][f]
            for (int nt = 0; nt < 8; ++nt) {
                f4 v = accT[nt];
                h4 h = {(_Float16)v.x, (_Float16)v.y, (_Float16)v.z, (_Float16)v.w};
                *(h4*)(&Ts[(nt * 16 + l16) * LDSP + wb + quad * 4]) = h;
                v = accV[nt];
                h4 g = {(_Float16)v.x, (_Float16)v.y, (_Float16)v.z, (_Float16)v.w};
                *(h4*)(&Vs[(wb + l16) * LDSP + nt * 16 + quad * 4]) = g;  // transposed: Vs[d][u]
            }
        }
        __syncthreads();  // Ts, Vs ready

        // ---- phase 2: S^T[u][w] = sum_f X[u][f] T'[w][f]; wave owns w-strip ----
        f4 acc[8];
        for (int mt = 0; mt < 8; ++mt) acc[mt] = (f4){0.f, 0.f, 0.f, 0.f};
        for (int f0 = 0; f0 < 4; ++f0) {
            h8 bt = *(const h8*)(&Ts[(wb + l16) * LDSP + f0 * 32 + quad * 8]);  // own strip only
            h8 a[8];
            for (int mt = 0; mt < 8; ++mt)
                a[mt] = *(const h8*)(&X[(mt * 16 + l16) * LDSP + f0 * 32 + quad * 8]);
            for (int mt = 0; mt < 8; ++mt)
                acc[mt] = __builtin_amdgcn_mfma_f32_16x16x32_f16(a[mt], bt, acc[mt], 0, 0, 0);
        }
        // softmax over u for lane's column w = wb+l16 (u spread across quads + mt tiles)
        {
            float m = -1e30f;
            for (int mt = 0; mt < 8; ++mt) {
                f4 v = acc[mt];
                m = fmaxf(m, fmaxf(fmaxf(v.x, v.y), fmaxf(v.z, v.w)));
            }
            m = fmaxf(m, __shfl_xor(m, 16, 64));
            m = fmaxf(m, __shfl_xor(m, 32, 64));
            float s = 0.f;
            for (int mt = 0; mt < 8; ++mt) {
                f4 v = acc[mt];
                v.x = __expf(v.x - m); v.y = __expf(v.y - m);
                v.z = __expf(v.z - m); v.w = __expf(v.w - m);
                acc[mt] = v;
                s += v.x + v.y + v.z + v.w;
            }
            s += __shfl_xor(s, 16, 64);
            s += __shfl_xor(s, 32, 64);
            float inv = 1.0f / s;
            // P quad-regs u-contiguous -> packed write into OWN strip of Ts (only this
            // wave ever reads Ts rows [wb,wb+16) in phases 2/3 -> no barrier needed)
            for (int mt = 0; mt < 8; ++mt) {
                f4 v = acc[mt];
                h4 h = {(_Float16)(v.x * inv), (_Float16)(v.y * inv),
                        (_Float16)(v.z * inv), (_Float16)(v.w * inv)};
                *(h4*)(&Ts[(wb + l16) * LDSP + mt * 16 + quad * 4]) = h;
            }
        }

        // ---- phase 3: O[w][d] = sum_u P[w][u] V[u][d] ----
        for (int nt = 0; nt < 8; ++nt) acc[nt] = (f4){0.f, 0.f, 0.f, 0.f};
        for (int u0 = 0; u0 < 4; ++u0) {
            h8 ap = *(const h8*)(&Ts[(wb + l16) * LDSP + u0 * 32 + quad * 8]);  // P own strip
            h8 b[8];
            for (int nt = 0; nt < 8; ++nt)
                b[nt] = *(const h8*)(&Vs[(nt * 16 + l16) * LDSP + u0 * 32 + quad * 8]);
            for (int nt = 0; nt < 8; ++nt)
                acc[nt] = __builtin_amdgcn_mfma_f32_16x16x32_f16(ap, b[nt], acc[nt], 0, 0, 0);
        }
        // C/D: col = d = nt*16+l16, row = w = wb+quad*4+r -> 64B-run coalesced stores
        float* ob = out + base0 + (size_t)it * (128 * 128);
        for (int nt = 0; nt < 8; ++nt) {
            f4 v = acc[nt];
            int w0 = wb + quad * 4;
            int d  = nt * 16 + l16;
            ob[(size_t)(w0 + 0) * 128 + d] = v.x;
            ob[(size_t)(w0 + 1) * 128 + d] = v.y;
            ob[(size_t)(w0 + 2) * 128 + d] = v.z;
            ob[(size_t)(w0 + 3) * 128 + d] = v.w;
        }
    }
}

extern "C" void kernel_launch(void* const* d_in, const int* in_sizes, int n_in,
                              void* d_out, int out_size, void* d_ws, size_t ws_size,
                              hipStream_t stream) {
    const float* x  = (const float*)d_in[0];
    const float* Wq = (const float*)d_in[1];
    const float* bq = (const float*)d_in[2];
    const float* Wk = (const float*)d_in[3];
    // bk (d_in[4]) drops out of softmax entirely
    const float* Wv = (const float*)d_in[5];
    const float* bv = (const float*)d_in[6];

    _Float16* Mt  = (_Float16*)d_ws;            // 32 KiB
    _Float16* Wvh = Mt + 16384;                 // 32 KiB
    float*    ckp = (float*)(Wvh + 16384);      // 512 B

    prep_mt<<<64, 256, 0, stream>>>(Wq, Wk, Mt);
    prep_rest<<<1, 256, 0, stream>>>(Wv, Wk, bq, Wvh, ckp);
    attn<<<256, 512, 0, stream>>>(x, Mt, Wvh, ckp, bv, (float*)d_out);
}